// Round 28
// baseline (832.055 us; speedup 1.0000x reference)
//
#include <hip/hip_runtime.h>
#include <math.h>

static constexpr int B_  = 2;
static constexpr int N_  = 2048;
static constexpr int D_  = 256;
static constexpr int NH_ = 8;
static constexpr int L_  = 4;
static constexpr int DH_ = 32;
static constexpr int DQ_ = 128;   // 4*DH
static constexpr float FACTOR_ = 0.08838834764831845f;  // 0.5/sqrt(32)
static constexpr float LOG2E_  = 1.4426950408889634f;
static constexpr float EPS_ = 1e-5f;

typedef short    short8   __attribute__((ext_vector_type(8)));
typedef unsigned short us4 __attribute__((ext_vector_type(4)));
typedef unsigned short us8 __attribute__((ext_vector_type(8)));
typedef float    f32x4    __attribute__((ext_vector_type(4)));
typedef unsigned short us;

__device__ __forceinline__ us f2b(float f) {
  unsigned u = __float_as_uint(f);
  unsigned r = u + 0x7FFF + ((u >> 16) & 1);
  return (us)(r >> 16);
}
__device__ __forceinline__ float b2f(us u) {
  return __uint_as_float(((unsigned)u) << 16);
}
__device__ __forceinline__ float e2(float x) {
  return __builtin_amdgcn_exp2f(x);
}
__device__ __forceinline__ void gl_lds16(const void* g, void* l) {
  __builtin_amdgcn_global_load_lds(
      (const __attribute__((address_space(1))) void*)g,
      (__attribute__((address_space(3))) void*)l, 16, 0, 0);
}

// ---------------- LayerNorm: shuffle reduce, writes bf16 (+opt state copy) ---
__global__ __launch_bounds__(256) void ln_kernel(const float* __restrict__ X,
    const float* __restrict__ g, const float* __restrict__ b,
    us* __restrict__ Y, float* __restrict__ Xcopy) {
  __shared__ float p1[4], p2[4];
  int row = blockIdx.x, tid = threadIdx.x;
  float x = X[(size_t)row * D_ + tid];
  if (Xcopy) Xcopy[(size_t)row * D_ + tid] = x;
  float a = x, c = x * x;
  #pragma unroll
  for (int o = 32; o > 0; o >>= 1) {
    a += __shfl_xor(a, o, 64);
    c += __shfl_xor(c, o, 64);
  }
  if ((tid & 63) == 0) { p1[tid >> 6] = a; p2[tid >> 6] = c; }
  __syncthreads();
  float s1 = (p1[0] + p1[1]) + (p1[2] + p1[3]);
  float s2 = (p2[0] + p2[1]) + (p2[2] + p2[3]);
  float mean = s1 * (1.0f / D_);
  float var  = s2 * (1.0f / D_) - mean * mean;
  float inv  = rsqrtf(var + EPS_);
  Y[(size_t)row * D_ + tid] = f2b((x - mean) * inv * g[tid] + b[tid]);
}

// ---------------- V init: copy f32 state + bf16 mirror, 4 elems/thread ------
__global__ __launch_bounds__(256) void conv_copy(const float* __restrict__ X,
    float* __restrict__ Yf, us* __restrict__ Y) {
  size_t i = ((size_t)blockIdx.x * 256 + threadIdx.x) * 4;
  float4 v = *(const float4*)&X[i];
  *(float4*)&Yf[i] = v;
  us4 o = { f2b(v.x), f2b(v.y), f2b(v.z), f2b(v.w) };
  *(us4*)&Y[i] = o;
}

// ---------------- weight convert + transpose, ALL LAYERS ---------------------
struct WConvDesc {
  const float* src[9];
  unsigned dst[9];
  int K[9];
  int N[9];
  int start[10];
  int lstride[9];
};
__global__ __launch_bounds__(256) void wconv_kernel(WConvDesc d, us* __restrict__ Wb) {
  __shared__ float T[64][65];
  int bid0 = blockIdx.x, tid = threadIdx.x;
  int lay = bid0 / 480;
  int bid = bid0 - lay * 480;
  int j = 0;
  #pragma unroll
  for (int q = 0; q < 8; q++) if (bid >= d.start[q + 1]) j = q + 1;
  int t = bid - d.start[j];
  int K = d.K[j], N = d.N[j];
  int tpr = N >> 6;
  int tk = t / tpr, tn = t - tk * tpr;
  const float* src = d.src[j] + (size_t)lay * d.lstride[j];
  us* dst = Wb + (size_t)lay * 1966080u + d.dst[j];
  #pragma unroll
  for (int i = 0; i < 4; i++) {
    int r = i * 16 + (tid >> 4), c = (tid & 15) * 4;
    *(float4*)&T[r][c] = *(const float4*)&src[(size_t)(tk * 64 + r) * N + tn * 64 + c];
  }
  __syncthreads();
  #pragma unroll
  for (int i = 0; i < 4; i++) {
    int n = i * 16 + (tid >> 4), k = (tid & 15) * 4;
    us4 o = { f2b(T[k][n]), f2b(T[k + 1][n]), f2b(T[k + 2][n]), f2b(T[k + 3][n]) };
    *(us4*)&dst[(size_t)(tn * 64 + n) * K + tk * 64 + k] = o;
  }
}

// ---------------- QKV GEMM + Vvv GEMM + bias precombine, one dispatch --------
// grid (36, 66): by<32 -> 128x64 QKV tile; 32<=by<54 -> 64x64 Vvv tile
// (linear id, 768 active); by>=54 -> grid-stride biascomb (tail filler).
__global__ __launch_bounds__(256, 3) void gemm_qkv(const us* __restrict__ A,
    const us* __restrict__ Wt, const float* __restrict__ bias,
    const float* __restrict__ bias2, const float* __restrict__ bias3,
    us* __restrict__ Cb, const float* __restrict__ R,
    const float* __restrict__ Dq, us* __restrict__ BiasOut, float oscale,
    const us* __restrict__ Vbm, const us* __restrict__ WtVV,
    us* __restrict__ Vvb) {
  constexpr int BM = 128, BN = 64, K = 256, Nc = 2304;
  __shared__ us As[2][BM * 64];
  __shared__ us Bs[2][BN * 64];
  const int tid = threadIdx.x;

  if (blockIdx.y >= 54) {            // ---- bias precombine path ----
    const size_t total = (size_t)B_ * N_ * N_;
    const int nb = (gridDim.y - 54) * gridDim.x;
    const int bidl = (blockIdx.y - 54) * gridDim.x + blockIdx.x;
    const size_t step = (size_t)nb * 256 * 8;
    for (size_t i = ((size_t)bidl * 256 + tid) * 8; i < total; i += step) {
      float4 r0 = *(const float4*)&R[i];
      float4 r1 = *(const float4*)&R[i + 4];
      float4 d0 = *(const float4*)&Dq[i];
      float4 d1 = *(const float4*)&Dq[i + 4];
      us8 o = { f2b((r0.x + d0.x) * LOG2E_), f2b((r0.y + d0.y) * LOG2E_),
                f2b((r0.z + d0.z) * LOG2E_), f2b((r0.w + d0.w) * LOG2E_),
                f2b((r1.x + d1.x) * LOG2E_), f2b((r1.y + d1.y) * LOG2E_),
                f2b((r1.z + d1.z) * LOG2E_), f2b((r1.w + d1.w) * LOG2E_) };
      *(us8*)&BiasOut[i] = o;
    }
    return;
  }

  const int w = tid >> 6, l = tid & 63;
  const int lx = l & 15, ly = l >> 4;
  const int wr = w >> 1, wc = w & 1;
  const int swz = (lx & 7) << 4;
  const size_t rowb = (size_t)K * 2;

  if (blockIdx.y >= 32) {            // ---- Vvv 64x64 GEMM path ----
    const int q = (blockIdx.y - 32) * 36 + blockIdx.x;
    if (q >= 768) return;
    const int bn = q & 3, bm = q >> 2;
    const char* Ag = (const char*)Vbm + (size_t)(bm * 64) * K * 2;
    const char* Bg = (const char*)WtVV + (size_t)(bn * 64) * K * 2;

    #define GSTAGE2(buf, k0)                                                  \
      do {                                                                    \
        _Pragma("unroll")                                                     \
        for (int j = 0; j < 2; j++) {                                         \
          int o = j * 4096 + tid * 16;                                        \
          int r = o >> 7, cb = o & 127;                                       \
          int sc = cb ^ ((r & 7) << 4);                                       \
          gl_lds16(Ag + (size_t)r * rowb + (size_t)(k0) * 2 + sc,             \
                   &As[buf][(j * 4096 + w * 1024) >> 1]);                     \
          gl_lds16(Bg + (size_t)r * rowb + (size_t)(k0) * 2 + sc,             \
                   &Bs[buf][(j * 4096 + w * 1024) >> 1]);                     \
        }                                                                     \
      } while (0)

    f32x4 acc[2][2];
    #pragma unroll
    for (int i = 0; i < 2; i++)
      #pragma unroll
      for (int j = 0; j < 2; j++) acc[i][j] = (f32x4){0.f, 0.f, 0.f, 0.f};

    int cur = 0;
    GSTAGE2(0, 0);
    __syncthreads();
    for (int k0 = 0; k0 < K; k0 += 64) {
      if (k0 + 64 < K) GSTAGE2(cur ^ 1, k0 + 64);
      #pragma unroll
      for (int s = 0; s < 2; s++) {
        short8 af[2], bf[2];
        #pragma unroll
        for (int mt = 0; mt < 2; mt++)
          af[mt] = *(const short8*)
              &As[cur][(((wr * 32 + mt * 16 + lx) * 128) + ((s * 64 + ly * 16) ^ swz)) >> 1];
        #pragma unroll
        for (int nt = 0; nt < 2; nt++)
          bf[nt] = *(const short8*)
              &Bs[cur][(((wc * 32 + nt * 16 + lx) * 128) + ((s * 64 + ly * 16) ^ swz)) >> 1];
        __builtin_amdgcn_s_setprio(1);
        #pragma unroll
        for (int mt = 0; mt < 2; mt++)
          #pragma unroll
          for (int nt = 0; nt < 2; nt++)
            acc[mt][nt] = __builtin_amdgcn_mfma_f32_16x16x32_bf16(af[mt], bf[nt], acc[mt][nt], 0, 0, 0);
        __builtin_amdgcn_s_setprio(0);
      }
      __syncthreads();
      cur ^= 1;
    }
    #undef GSTAGE2

    #pragma unroll
    for (int nt = 0; nt < 2; nt++) {
      const int n = bn * 64 + wc * 32 + nt * 16 + lx;
      #pragma unroll
      for (int mt = 0; mt < 2; mt++) {
        #pragma unroll
        for (int r = 0; r < 4; r++) {
          const int m = bm * 64 + wr * 32 + mt * 16 + ly * 4 + r;
          Vvb[(size_t)m * 256 + n] = f2b(acc[mt][nt][r]);
        }
      }
    }
    return;
  }

  // ---- QKV 128x64 GEMM path ----
  const int bn = blockIdx.x, bm = blockIdx.y;
  const char* Ag = (const char*)A + (size_t)(bm * BM) * K * 2;
  const char* Bg = (const char*)Wt + (size_t)(bn * BN) * K * 2;

  #define GSTAGE(buf, k0)                                                     \
    do {                                                                      \
      _Pragma("unroll")                                                       \
      for (int j = 0; j < 4; j++) {                                           \
        int o = j * 4096 + tid * 16;                                          \
        int r = o >> 7, cb = o & 127;                                         \
        int sc = cb ^ ((r & 7) << 4);                                         \
        gl_lds16(Ag + (size_t)r * rowb + (size_t)(k0) * 2 + sc,               \
                 &As[buf][(j * 4096 + w * 1024) >> 1]);                       \
      }                                                                       \
      _Pragma("unroll")                                                       \
      for (int j = 0; j < 2; j++) {                                           \
        int o = j * 4096 + tid * 16;                                          \
        int r = o >> 7, cb = o & 127;                                         \
        int sc = cb ^ ((r & 7) << 4);                                         \
        gl_lds16(Bg + (size_t)r * rowb + (size_t)(k0) * 2 + sc,               \
                 &Bs[buf][(j * 4096 + w * 1024) >> 1]);                       \
      }                                                                       \
    } while (0)

  f32x4 acc[4][2];
  #pragma unroll
  for (int i = 0; i < 4; i++)
    #pragma unroll
    for (int j = 0; j < 2; j++) acc[i][j] = (f32x4){0.f, 0.f, 0.f, 0.f};

  int cur = 0;
  GSTAGE(0, 0);
  __syncthreads();
  for (int k0 = 0; k0 < K; k0 += 64) {
    if (k0 + 64 < K) GSTAGE(cur ^ 1, k0 + 64);
    #pragma unroll
    for (int s = 0; s < 2; s++) {
      short8 af[4], bf[2];
      #pragma unroll
      for (int mt = 0; mt < 4; mt++)
        af[mt] = *(const short8*)
            &As[cur][(((wr * 64 + mt * 16 + lx) * 128) + ((s * 64 + ly * 16) ^ swz)) >> 1];
      #pragma unroll
      for (int nt = 0; nt < 2; nt++)
        bf[nt] = *(const short8*)
            &Bs[cur][(((wc * 32 + nt * 16 + lx) * 128) + ((s * 64 + ly * 16) ^ swz)) >> 1];
      __builtin_amdgcn_s_setprio(1);
      #pragma unroll
      for (int mt = 0; mt < 4; mt++)
        #pragma unroll
        for (int nt = 0; nt < 2; nt++)
          acc[mt][nt] = __builtin_amdgcn_mfma_f32_16x16x32_bf16(af[mt], bf[nt], acc[mt][nt], 0, 0, 0);
      __builtin_amdgcn_s_setprio(0);
    }
    __syncthreads();
    cur ^= 1;
  }
  #undef GSTAGE

  #pragma unroll
  for (int nt = 0; nt < 2; nt++) {
    const int n = bn * BN + wc * 32 + nt * 16 + lx;
    float bval, osc = oscale;
    if (n < 1024)      { bval = bias[n]; }
    else if (n < 2048) { bval = bias2[n - 1024]; osc = 1.0f; }
    else               { bval = bias3[n - 2048]; osc = 1.0f; }
    #pragma unroll
    for (int mt = 0; mt < 4; mt++) {
      #pragma unroll
      for (int r = 0; r < 4; r++) {
        const int m = bm * BM + wr * 64 + mt * 16 + ly * 4 + r;
        float v = acc[mt][nt][r] + bval;
        Cb[(size_t)m * Nc + n] = f2b(v * osc);
      }
    }
  }
}

// ---------------- gemm_v2: asymmetric BM x BN tiles, gl_lds dbuf -------------
template<int BM, int BN, int BIAS, int ACC, int SILU, int WF, int WB, int QKV, int MINW>
__global__ __launch_bounds__(256, MINW) void gemm_v2(const us* __restrict__ A,
    const us* __restrict__ Wt, const float* __restrict__ bias,
    const float* __restrict__ bias2, const float* __restrict__ bias3,
    float* __restrict__ Cf, us* __restrict__ Cb,
    int M, int K, int Nc, float oscale) {
  constexpr int NFM = BM / 32, NFN = BN / 32;
  constexpr int WSM = NFM * 16, WSN = NFN * 16;
  constexpr int NLA = BM / 32, NLB = BN / 32;
  __shared__ us As[2][BM * 64];
  __shared__ us Bs[2][BN * 64];
  const int tid = threadIdx.x;
  const int w = tid >> 6, l = tid & 63;
  const int lx = l & 15, ly = l >> 4;
  const int wr = w >> 1, wc = w & 1;
  const int bn = blockIdx.x, bm = blockIdx.y;
  const int swz = (lx & 7) << 4;
  const char* Ag = (const char*)A + (size_t)(bm * BM) * K * 2;
  const char* Bg = (const char*)Wt + (size_t)(bn * BN) * K * 2;
  const size_t rowb = (size_t)K * 2;

  #define GSTAGE(buf, k0)                                                     \
    do {                                                                      \
      _Pragma("unroll")                                                       \
      for (int j = 0; j < NLA; j++) {                                         \
        int o = j * 4096 + tid * 16;                                          \
        int r = o >> 7, cb = o & 127;                                         \
        int sc = cb ^ ((r & 7) << 4);                                         \
        gl_lds16(Ag + (size_t)r * rowb + (size_t)(k0) * 2 + sc,               \
                 &As[buf][(j * 4096 + w * 1024) >> 1]);                       \
      }                                                                       \
      _Pragma("unroll")                                                       \
      for (int j = 0; j < NLB; j++) {                                         \
        int o = j * 4096 + tid * 16;                                          \
        int r = o >> 7, cb = o & 127;                                         \
        int sc = cb ^ ((r & 7) << 4);                                         \
        gl_lds16(Bg + (size_t)r * rowb + (size_t)(k0) * 2 + sc,               \
                 &Bs[buf][(j * 4096 + w * 1024) >> 1]);                       \
      }                                                                       \
    } while (0)

  f32x4 acc[NFM][NFN];
  #pragma unroll
  for (int i = 0; i < NFM; i++)
    #pragma unroll
    for (int j = 0; j < NFN; j++) acc[i][j] = (f32x4){0.f, 0.f, 0.f, 0.f};

  int cur = 0;
  GSTAGE(0, 0);
  __syncthreads();
  for (int k0 = 0; k0 < K; k0 += 64) {
    if (k0 + 64 < K) GSTAGE(cur ^ 1, k0 + 64);
    #pragma unroll
    for (int s = 0; s < 2; s++) {
      short8 af[NFM], bf[NFN];
      #pragma unroll
      for (int mt = 0; mt < NFM; mt++)
        af[mt] = *(const short8*)
            &As[cur][(((wr * WSM + mt * 16 + lx) * 128) + ((s * 64 + ly * 16) ^ swz)) >> 1];
      #pragma unroll
      for (int nt = 0; nt < NFN; nt++)
        bf[nt] = *(const short8*)
            &Bs[cur][(((wc * WSN + nt * 16 + lx) * 128) + ((s * 64 + ly * 16) ^ swz)) >> 1];
      __builtin_amdgcn_s_setprio(1);
      #pragma unroll
      for (int mt = 0; mt < NFM; mt++)
        #pragma unroll
        for (int nt = 0; nt < NFN; nt++)
          acc[mt][nt] = __builtin_amdgcn_mfma_f32_16x16x32_bf16(af[mt], bf[nt], acc[mt][nt], 0, 0, 0);
      __builtin_amdgcn_s_setprio(0);
    }
    __syncthreads();
    cur ^= 1;
  }
  #undef GSTAGE

  #pragma unroll
  for (int nt = 0; nt < NFN; nt++) {
    const int n = bn * BN + wc * WSN + nt * 16 + lx;
    float bval = 0.f, osc = oscale;
    if (QKV) {
      if (n < 1024)      { bval = bias[n]; }
      else if (n < 2048) { bval = bias2[n - 1024]; osc = 1.0f; }
      else               { bval = bias3[n - 2048]; osc = 1.0f; }
    } else if (BIAS) {
      bval = bias[n];
    }
    #pragma unroll
    for (int mt = 0; mt < NFM; mt++) {
      #pragma unroll
      for (int r = 0; r < 4; r++) {
        const int m = bm * BM + wr * WSM + mt * 16 + ly * 4 + r;
        float v = acc[mt][nt][r] + bval;
        if (SILU) v = v / (1.f + __expf(-v));
        size_t idx = (size_t)m * Nc + n;
        if (ACC) v += Cf[idx];
        if (WF) Cf[idx] = v;
        if (WB) Cb[idx] = f2b(v * osc);
      }
    }
  }
}

// ---------------- merged Wo+Wvo GEMM: H path (bm<64) + V path ----------------
__global__ __launch_bounds__(256, 3) void gemm_wo(const us* __restrict__ Hres,
    const us* __restrict__ Vres, const us* __restrict__ WtO,
    const us* __restrict__ WtVO, const float* __restrict__ bo,
    float* __restrict__ Hs, float* __restrict__ Vs, us* __restrict__ Vb) {
  constexpr int K = 256, Nc = 256;
  __shared__ us As[2][64 * 64];
  __shared__ us Bs[2][64 * 64];
  const int tid = threadIdx.x;
  const int w = tid >> 6, l = tid & 63;
  const int lx = l & 15, ly = l >> 4;
  const int wr = w >> 1, wc = w & 1;
  const int bn = blockIdx.x, bm = blockIdx.y;
  const bool isH = bm < 64;
  const int mb = isH ? bm : bm - 64;
  const int swz = (lx & 7) << 4;
  const char* Ag = (const char*)(isH ? Hres : Vres) + (size_t)(mb * 64) * K * 2;
  const char* Bg = (const char*)(isH ? WtO : WtVO) + (size_t)(bn * 64) * K * 2;
  const size_t rowb = (size_t)K * 2;

  #define GSTAGE(buf, k0)                                                     \
    do {                                                                      \
      _Pragma("unroll")                                                       \
      for (int j = 0; j < 2; j++) {                                           \
        int o = j * 4096 + tid * 16;                                          \
        int r = o >> 7, cb = o & 127;                                         \
        int sc = cb ^ ((r & 7) << 4);                                         \
        gl_lds16(Ag + (size_t)r * rowb + (size_t)(k0) * 2 + sc,               \
                 &As[buf][(j * 4096 + w * 1024) >> 1]);                       \
        gl_lds16(Bg + (size_t)r * rowb + (size_t)(k0) * 2 + sc,               \
                 &Bs[buf][(j * 4096 + w * 1024) >> 1]);                       \
      }                                                                       \
    } while (0)

  f32x4 acc[2][2];
  #pragma unroll
  for (int i = 0; i < 2; i++)
    #pragma unroll
    for (int j = 0; j < 2; j++) acc[i][j] = (f32x4){0.f, 0.f, 0.f, 0.f};

  int cur = 0;
  GSTAGE(0, 0);
  __syncthreads();
  for (int k0 = 0; k0 < K; k0 += 64) {
    if (k0 + 64 < K) GSTAGE(cur ^ 1, k0 + 64);
    #pragma unroll
    for (int s = 0; s < 2; s++) {
      short8 af[2], bf[2];
      #pragma unroll
      for (int mt = 0; mt < 2; mt++)
        af[mt] = *(const short8*)
            &As[cur][(((wr * 32 + mt * 16 + lx) * 128) + ((s * 64 + ly * 16) ^ swz)) >> 1];
      #pragma unroll
      for (int nt = 0; nt < 2; nt++)
        bf[nt] = *(const short8*)
            &Bs[cur][(((wc * 32 + nt * 16 + lx) * 128) + ((s * 64 + ly * 16) ^ swz)) >> 1];
      __builtin_amdgcn_s_setprio(1);
      #pragma unroll
      for (int mt = 0; mt < 2; mt++)
        #pragma unroll
        for (int nt = 0; nt < 2; nt++)
          acc[mt][nt] = __builtin_amdgcn_mfma_f32_16x16x32_bf16(af[mt], bf[nt], acc[mt][nt], 0, 0, 0);
      __builtin_amdgcn_s_setprio(0);
    }
    __syncthreads();
    cur ^= 1;
  }
  #undef GSTAGE

  #pragma unroll
  for (int nt = 0; nt < 2; nt++) {
    const int n = bn * 64 + wc * 32 + nt * 16 + lx;
    const float bval = isH ? bo[n] : 0.f;
    #pragma unroll
    for (int mt = 0; mt < 2; mt++) {
      #pragma unroll
      for (int r = 0; r < 4; r++) {
        const int m = mb * 64 + wr * 32 + mt * 16 + ly * 4 + r;
        size_t idx = (size_t)m * Nc + n;
        float v = acc[mt][nt][r] + bval;
        if (isH) {
          Hs[idx] += v;
        } else {
          float nv = Vs[idx] + v;
          Vs[idx] = nv;
          Vb[idx] = f2b(nv);
        }
      }
    }
  }
}

// ---------------- W2 GEMM with fused final H/V update ------------------------
__global__ __launch_bounds__(256, 3) void gemm_w2(const us* __restrict__ A,
    const us* __restrict__ Wt, const float* __restrict__ b2,
    const float* __restrict__ Vp, float* __restrict__ Hs,
    float* __restrict__ Vs, us* __restrict__ Vb) {
  constexpr int K = 1024;
  __shared__ us As[2][64 * 64];
  __shared__ us Bs[2][64 * 64];
  const int tid = threadIdx.x;
  const int w = tid >> 6, l = tid & 63;
  const int lx = l & 15, ly = l >> 4;
  const int wr = w >> 1, wc = w & 1;
  const int bn = blockIdx.x, bm = blockIdx.y;
  const int swz = (lx & 7) << 4;
  const char* Ag = (const char*)A + (size_t)(bm * 64) * K * 2;
  const char* Bg = (const char*)Wt + (size_t)(bn * 64) * K * 2;
  const size_t rowb = (size_t)K * 2;

  #define GSTAGE(buf, k0)                                                     \
    do {                                                                      \
      _Pragma("unroll")                                                       \
      for (int j = 0; j < 2; j++) {                                           \
        int o = j * 4096 + tid * 16;                                          \
        int r = o >> 7, cb = o & 127;                                         \
        int sc = cb ^ ((r & 7) << 4);                                         \
        gl_lds16(Ag + (size_t)r * rowb + (size_t)(k0) * 2 + sc,               \
                 &As[buf][(j * 4096 + w * 1024) >> 1]);                       \
        gl_lds16(Bg + (size_t)r * rowb + (size_t)(k0) * 2 + sc,               \
                 &Bs[buf][(j * 4096 + w * 1024) >> 1]);                       \
      }                                                                      \
    } while (0)

  f32x4 acc[2][2];
  #pragma unroll
  for (int i = 0; i < 2; i++)
    #pragma unroll
    for (int j = 0; j < 2; j++) acc[i][j] = (f32x4){0.f, 0.f, 0.f, 0.f};

  int cur = 0;
  GSTAGE(0, 0);
  __syncthreads();
  for (int k0 = 0; k0 < K; k0 += 64) {
    if (k0 + 64 < K) GSTAGE(cur ^ 1, k0 + 64);
    #pragma unroll
    for (int s = 0; s < 2; s++) {
      short8 af[2], bf[2];
      #pragma unroll
      for (int mt = 0; mt < 2; mt++)
        af[mt] = *(const short8*)
            &As[cur][(((wr * 32 + mt * 16 + lx) * 128) + ((s * 64 + ly * 16) ^ swz)) >> 1];
      #pragma unroll
      for (int nt = 0; nt < 2; nt++)
        bf[nt] = *(const short8*)
            &Bs[cur][(((wc * 32 + nt * 16 + lx) * 128) + ((s * 64 + ly * 16) ^ swz)) >> 1];
      __builtin_amdgcn_s_setprio(1);
      #pragma unroll
      for (int mt = 0; mt < 2; mt++)
        #pragma unroll
        for (int nt = 0; nt < 2; nt++)
          acc[mt][nt] = __builtin_amdgcn_mfma_f32_16x16x32_bf16(af[mt], bf[nt], acc[mt][nt], 0, 0, 0);
      __builtin_amdgcn_s_setprio(0);
    }
    __syncthreads();
    cur ^= 1;
  }
  #undef GSTAGE

  const bool isH = (bn < 4);
  #pragma unroll
  for (int nt = 0; nt < 2; nt++) {
    const int n = bn * 64 + wc * 32 + nt * 16 + lx;
    const float bval = b2[n];
    #pragma unroll
    for (int mt = 0; mt < 2; mt++) {
      #pragma unroll
      for (int r = 0; r < 4; r++) {
        const int m = bm * 64 + wr * 32 + mt * 16 + ly * 4 + r;
        float v = acc[mt][nt][r] + bval;
        if (isH) {
          Hs[(size_t)m * D_ + n] += v;
        } else {
          const int j = n - 256;
          #pragma unroll
          for (int c = 0; c < 3; c++) {
            size_t vi = ((size_t)m * 3 + c) * D_ + j;
            float nv = Vs[vi] + v * Vp[((size_t)m * 3 + c) * 512 + 256 + j];
            Vs[vi] = nv;
            Vb[vi] = f2b(nv);
          }
        }
      }
    }
  }
}

// ---------------- pack V_attn transposed: Vt[b][h][128][N] bf16 --------------
__global__ __launch_bounds__(256) void pack_vattn_t(const us* __restrict__ QKVb,
    const us* __restrict__ Vv, us* __restrict__ Vt) {
  __shared__ us T[64][136];
  const int bid = blockIdx.x;
  const int nt = bid & 31, hh = (bid >> 5) & 7, b = bid >> 8;
  const int n0 = nt * 64;
  const int tid = threadIdx.x;
  {
    const int nn = tid >> 2, part = tid & 3;
    const size_t row = (size_t)(b * N_ + n0 + nn);
    const us* src = (part == 0) ? (QKVb + row * 2304 + 2048 + hh * DH_)
                                : (Vv + (row * 3 + (part - 1)) * D_ + hh * DH_);
    #pragma unroll
    for (int jj = 0; jj < 32; jj += 8)
      *(us8*)&T[nn][part * 32 + jj] = *(const us8*)(src + jj);
  }
  __syncthreads();
  const int d = tid >> 1, half = tid & 1;
  size_t ob = ((size_t)(b * NH_ + hh) * DQ_ + d) * (size_t)N_ + n0 + half * 32;
  #pragma unroll
  for (int i = 0; i < 32; i += 8) {
    us8 o;
    #pragma unroll
    for (int e = 0; e < 8; e++) o[e] = T[half * 32 + i + e][d];
    *(us8*)&Vt[ob + i] = o;
  }
}

// ---------------- MFMA flash attention, KV-split-2, 40KB LDS (4 blocks/CU) ---
// grid 1024 = exactly 4 blocks x 256 CUs. Plds unpadded [4][16][64] with XOR
// swizzle. minw=3 (NOT 4): lets compiler keep ~80 VGPR (no spills); runtime
// occupancy still reaches 4 blocks/CU since 80<=128 VGPR and LDS=40960.
__global__ __launch_bounds__(256, 3) void attn_mfma(
    const us* __restrict__ QKVb,     // [B*N][2304]: Q(FACTOR*log2e) | K | Hv
    const us* __restrict__ Vtb,      // [B][NH][128][N]
    const us* __restrict__ bias,     // layer slice [B][N][N] bf16
    float* __restrict__ Opart,       // [2][B*N][NH][128] f32 unnormalized
    float* __restrict__ Ml) {        // [2][B*N][NH][2] f32 (m, l)
  __shared__ us Kt[8192];            // 16KB: [64 m-rows][256B]
  __shared__ us Vt[8192];            // 16KB: [128 d-rows][128B]
  __shared__ us Plds[4][16][64];     // 8KB (total 40960 = 160KB/4 exactly)
  const int bid = blockIdx.x;
  const int h  = bid & 7;
  const int g  = bid >> 3;
  const int qt = g & 31;
  const int bs = g >> 5;
  const int b  = bs & 1;
  const int sp = bs >> 1;
  const int kv0 = sp * 1024;
  const int tid = threadIdx.x;
  const int w  = tid >> 6;
  const int l  = tid & 63;
  const int lx = l & 15;
  const int ly = l >> 4;
  const int qrow = qt * 64 + w * 16 + lx;
  const int swz = (lx & 7) << 4;

  short8 qf[4];
  {
    const us* qp = QKVb + (size_t)(b * N_ + qrow) * 2304 + h * DQ_ + ly * 8;
    #pragma unroll
    for (int s = 0; s < 4; s++) qf[s] = *(const short8*)(qp + s * 32);
  }
  const char* kg = (const char*)QKVb + (size_t)b * N_ * 4608 + 2048 + h * 256;
  const char* vg = (const char*)(Vtb + ((size_t)(b * NH_ + h) * DQ_) * (size_t)N_);
  const us* bbase = bias + ((size_t)b * N_ + qrow) * N_;
  char* prow = (char*)&Plds[w][lx][0];

  us8 kreg[4], vreg[4];
  #define LOADKV(m0)                                                          \
    do {                                                                      \
      _Pragma("unroll")                                                       \
      for (int j = 0; j < 4; j++) {                                           \
        int o = j * 4096 + tid * 16;                                          \
        int rk = o >> 8, ck = o & 255;                                        \
        kreg[j] = *(const us8*)(kg + (size_t)((m0) + rk) * 4608 +             \
                                (ck ^ ((rk & 7) << 4)));                      \
        int rv = o >> 7, cv = o & 127;                                        \
        vreg[j] = *(const us8*)(vg + (size_t)rv * (N_ * 2) +                  \
                                (size_t)(m0) * 2 + (cv ^ ((rv & 7) << 4)));   \
      }                                                                       \
    } while (0)
  #define WRITEKV()                                                           \
    do {                                                                      \
      _Pragma("unroll")                                                       \
      for (int j = 0; j < 4; j++) {                                           \
        *(us8*)&Kt[j * 2048 + tid * 8] = kreg[j];                             \
        *(us8*)&Vt[j * 2048 + tid * 8] = vreg[j];                             \
      }                                                                       \
    } while (0)

  float m_run = -3.0e38f, l_run = 0.f;   // l_run: per-lane partial
  f32x4 oacc[8];
  #pragma unroll
  for (int i = 0; i < 8; i++) oacc[i] = (f32x4){0.f, 0.f, 0.f, 0.f};

  LOADKV(kv0);
  WRITEKV();                 // compiler inserts vmcnt wait before ds_write
  LOADKV(kv0 + 64);          // prefetch chunk 1 into regs
  us4 bb[4];
  #pragma unroll
  for (int t = 0; t < 4; t++) bb[t] = *(const us4*)(bbase + kv0 + t * 16 + ly * 4);
  __syncthreads();

  const int kvend = kv0 + 1024;
  for (int mc0 = kv0; mc0 < kvend; mc0 += 64) {
    us4 bbn[4];
    if (mc0 + 64 < kvend) {
      #pragma unroll
      for (int t = 0; t < 4; t++)
        bbn[t] = *(const us4*)(bbase + mc0 + 64 + t * 16 + ly * 4);
    }
    f32x4 sacc[4];
    #pragma unroll
    for (int t = 0; t < 4; t++) sacc[t] = (f32x4){0.f, 0.f, 0.f, 0.f};
    __builtin_amdgcn_s_setprio(1);
    #pragma unroll
    for (int t = 0; t < 4; t++) {
      #pragma unroll
      for (int s = 0; s < 4; s++) {
        const short8 kf = *(const short8*)
            &Kt[((t * 16 + lx) * 256 + ((s * 64 + ly * 16) ^ swz)) >> 1];
        sacc[t] = __builtin_amdgcn_mfma_f32_16x16x32_bf16(kf, qf[s], sacc[t], 0, 0, 0);
      }
    }
    __builtin_amdgcn_s_setprio(0);
    float pvv[16];
    #pragma unroll
    for (int t = 0; t < 4; t++) {
      pvv[t*4+0] = sacc[t][0] + b2f(bb[t][0]);
      pvv[t*4+1] = sacc[t][1] + b2f(bb[t][1]);
      pvv[t*4+2] = sacc[t][2] + b2f(bb[t][2]);
      pvv[t*4+3] = sacc[t][3] + b2f(bb[t][3]);
    }
    float a8[8], a4[4];
    #pragma unroll
    for (int i = 0; i < 8; i++) a8[i] = fmaxf(pvv[i], pvv[i + 8]);
    #pragma unroll
    for (int i = 0; i < 4; i++) a4[i] = fmaxf(a8[i], a8[i + 4]);
    float mloc = fmaxf(fmaxf(a4[0], a4[1]), fmaxf(a4[2], a4[3]));
    if (!__all(mloc - m_run <= 11.54f)) {
      mloc = fmaxf(mloc, __shfl_xor(mloc, 16, 64));
      mloc = fmaxf(mloc, __shfl_xor(mloc, 32, 64));
      float m_new = fmaxf(m_run, mloc);
      float scale = e2(m_run - m_new);
      l_run *= scale;
      #pragma unroll
      for (int i = 0; i < 8; i++) {
        oacc[i][0] *= scale; oacc[i][1] *= scale;
        oacc[i][2] *= scale; oacc[i][3] *= scale;
      }
      m_run = m_new;
    }
    float s8[8], s4[4];
    #pragma unroll
    for (int i = 0; i < 16; i++) pvv[i] = e2(pvv[i] - m_run);
    #pragma unroll
    for (int i = 0; i < 8; i++) s8[i] = pvv[i] + pvv[i + 8];
    #pragma unroll
    for (int i = 0; i < 4; i++) s4[i] = s8[i] + s8[i + 4];
    l_run += (s4[0] + s4[1]) + (s4[2] + s4[3]);
    #pragma unroll
    for (int t = 0; t < 4; t++) {
      us4 pk = { f2b(pvv[t*4+0]), f2b(pvv[t*4+1]), f2b(pvv[t*4+2]), f2b(pvv[t*4+3]) };
      *(us4*)(prow + (((t * 32 + ly * 8) ^ swz))) = pk;
    }
    short8 pf0 = *(const short8*)(prow + ((ly * 16) ^ swz));
    short8 pf1 = *(const short8*)(prow + ((64 + ly * 16) ^ swz));
    __builtin_amdgcn_s_setprio(1);
    #pragma unroll
    for (int dt = 0; dt < 8; dt++) {
      const int rb = (dt * 16 + lx) * 128;
      const short8 vf0 = *(const short8*)&Vt[(rb + ((ly * 16) ^ swz)) >> 1];
      const short8 vf1 = *(const short8*)&Vt[(rb + ((64 + ly * 16) ^ swz)) >> 1];
      oacc[dt] = __builtin_amdgcn_mfma_f32_16x16x32_bf16(vf0, pf0, oacc[dt], 0, 0, 0);
      oacc[dt] = __builtin_amdgcn_mfma_f32_16x16x32_bf16(vf1, pf1, oacc[dt], 0, 0, 0);
    }
    __builtin_amdgcn_s_setprio(0);
    __syncthreads();              // all waves done reading Kt/Vt
    if (mc0 + 64 < kvend) {
      WRITEKV();                  // chunk mc0+64 (regs -> LDS; vmcnt auto)
      if (mc0 + 128 < kvend) LOADKV(mc0 + 128);
      #pragma unroll
      for (int t = 0; t < 4; t++) bb[t] = bbn[t];
      __syncthreads();            // writes visible
    }
  }
  #undef LOADKV
  #undef WRITEKV
  l_run += __shfl_xor(l_run, 16, 64);
  l_run += __shfl_xor(l_run, 32, 64);
  // write unnormalized partials: O (f32), m, l  — merged exactly by combine
  const size_t grow = (size_t)(b * N_ + qrow);
  const size_t rh = ((size_t)sp * 4096 + grow) * 8 + h;
  float* op = Opart + rh * 128;
  #pragma unroll
  for (int dt = 0; dt < 8; dt++)
    *(f32x4*)&op[dt * 16 + ly * 4] = oacc[dt];
  if (ly == 0) {
    Ml[rh * 2 + 0] = m_run;
    Ml[rh * 2 + 1] = l_run;
  }
}

// ---------------- combine the two KV-split partials -> Hres/Vres bf16 --------
__global__ __launch_bounds__(256) void attn_combine(
    const float* __restrict__ Opart, const float* __restrict__ Ml,
    us* __restrict__ Hres, us* __restrict__ Vres) {
  const size_t grow = blockIdx.x;          // [0, B*N)
  const int tid = threadIdx.x;
  const int h = tid >> 5;                  // 8 heads x 32 lanes
  const int d = (tid & 31) * 4;            // 128 dims / 4
  const size_t rh0 = grow * 8 + h;
  const size_t rh1 = ((size_t)4096 + grow) * 8 + h;
  const float m0 = Ml[rh0 * 2], l0 = Ml[rh0 * 2 + 1];
  const float m1 = Ml[rh1 * 2], l1 = Ml[rh1 * 2 + 1];
  const float M  = fmaxf(m0, m1);
  const float w0 = e2(m0 - M), w1 = e2(m1 - M);
  const float inv = 1.0f / (l0 * w0 + l1 * w1);
  f32x4 o0 = *(const f32x4*)&Opart[rh0 * 128 + d];
  f32x4 o1 = *(const f32x4*)&Opart[rh1 * 128 + d];
  us4 pk;
  #pragma unroll
  for (int e = 0; e < 4; e++)
    pk[e] = f2b((o0[e] * w0 + o1[e] * w1) * inv);
  if (d < 32) {
    *(us4*)&Hres[grow * D_ + h * DH_ + d] = pk;
  } else {
    const int c = (d - DH_) >> 5, dd = (d - DH_) & 31;
    *(us4*)&Vres[(grow * 3 + c) * D_ + h * DH_ + dd] = pk;
  }
}

// ---------------- fused ln2 + scaler (shuffle reduce) ------------------------
__global__ __launch_bounds__(256) void ln2scaler(const float* __restrict__ H,
    const float* __restrict__ g, const float* __restrict__ b,
    const float* __restrict__ Vp, us* __restrict__ scal) {
  __shared__ float p1[4], p2[4];
  size_t row = blockIdx.x;
  int j = threadIdx.x;
  float x = H[row * D_ + j];
  float a = x, c = x * x;
  #pragma unroll
  for (int o = 32; o > 0; o >>= 1) {
    a += __shfl_xor(a, o, 64);
    c += __shfl_xor(c, o, 64);
  }
  if ((j & 63) == 0) { p1[j >> 6] = a; p2[j >> 6] = c; }
  __syncthreads();
  float s1 = (p1[0] + p1[1]) + (p1[2] + p1[3]);
  float s2 = (p2[0] + p2[1]) + (p2[2] + p2[3]);
  float mean = s1 * (1.0f / D_);
  float var  = s2 * (1.0f / D_) - mean * mean;
  float inv  = rsqrtf(var + EPS_);
  scal[row * 512 + j] = f2b((x - mean) * inv * g[j] + b[j]);
  float va = Vp[(row * 3 + 0) * 512 + j];
  float c1 = Vp[(row * 3 + 1) * 512 + j];
  float c2 = Vp[(row * 3 + 2) * 512 + j];
  scal[row * 512 + D_ + j] = f2b(sqrtf(va * va + c1 * c1 + c2 * c2));
}

extern "C" void kernel_launch(void* const* d_in, const int* in_sizes, int n_in,
                              void* d_out, int out_size, void* d_ws, size_t ws_size,
                              hipStream_t stream) {
  const float* H_in = (const float*)d_in[0];
  const float* V_in = (const float*)d_in[1];
  const float* Db   = (const float*)d_in[2];
  const float* rbf  = (const float*)d_in[3];
  const float* ln1g = (const float*)d_in[5];
  const float* ln1b = (const float*)d_in[6];
  const float* ln2g = (const float*)d_in[7];
  const float* ln2b = (const float*)d_in[8];
  const float* Wq  = (const float*)d_in[9];
  const float* bq  = (const float*)d_in[10];
  const float* Wk  = (const float*)d_in[11];
  const float* bk  = (const float*)d_in[12];
  const float* Wv  = (const float*)d_in[13];
  const float* bv  = (const float*)d_in[14];
  const float* Wvv = (const float*)d_in[15];
  const float* Wo  = (const float*)d_in[16];
  const float* bo  = (const float*)d_in[17];
  const float* Wvo = (const float*)d_in[18];
  const float* Wlv = (const float*)d_in[19];
  const float* W1  = (const float*)d_in[20];
  const float* b1  = (const float*)d_in[21];
  const float* W2  = (const float*)d_in[22];
  const float* b2  = (const float*)d_in[23];

  const size_t HN = (size_t)B_ * N_ * D_;        // 1,048,576
  const size_t VN = HN * 3;
  float* Hs = (float*)d_out;
  float* Vs = (float*)d_out + HN;
  float* ws = (float*)d_ws;
  // ---- workspace (float offsets) ----
  us*    bias_b = (us*)ws;                          // [0, 4,194,304)
  us*    Vb     = (us*)(ws + 5177344);              // [5177344, 6750208) persistent
  us*    Hnb    = (us*)(ws + 6750208);              // [6750208, 7274496)
  us*    QKVb   = (us*)(ws + 7274496);              // [7274496, 11993088)
  us*    Vtb    = (us*)(ws + 11993088);             // [11993088, 14090240)
  us*    Vvb    = (us*)(ws + 14090240);             // [14090240, 14876672)
  us*    Hres_b = (us*)(ws + 6750208);              // reuse Hnb (post-attn)
  us*    Vres_b = (us*)(ws + 14090240);             // overlays Vvb (post-attn)
  float* Vp     = ws + 7274496;                     // [7274496, 13565952) post-attn
  us*    scal_b = (us*)(ws + 13565952);             // [13565952, 14614528) post-Wvo
  us*    midb   = (us*)(ws + 15014528);             // [15014528, 17111680)
  us*    Wb4    = (us*)(ws + 17111680);             // [17111680, 21043840) 4-layer weights
  float* Opart  = ws + 21043840;                    // [21043840, 29432448) attn partials
  float* Mlp    = ws + 29432448;                    // [29432448, 29563520) m/l partials

  // V state init (f32 copy + bf16 mirror) in one pass
  conv_copy<<<3072, 256, 0, stream>>>(V_in, Vs, Vb);

  const int ROWS  = B_ * N_;       // 4096
  static const int wKs[9] = {256,256,256,256,256,256,256,512,1024};
  static const int wNs[9] = {1024,1024,256,256,256,256,512,1024,512};
  static const unsigned wOff[9] = {0,262144,524288,589824,655360,720896,786432,917504,1441792};
  static const int wStart[10] = {0,64,128,144,160,176,192,224,352,480};
  static const int wLstr[9] = {262144,262144,65536,65536,65536,65536,131072,524288,524288};

  // all-layer weight conversion: one dispatch, 1920 blocks
  {
    WConvDesc dsc;
    const float* srcs[9] = {Wq, Wk, Wv, Wvv, Wo, Wvo, Wlv, W1, W2};
    for (int j = 0; j < 9; j++) {
      dsc.src[j] = srcs[j]; dsc.dst[j] = wOff[j];
      dsc.K[j] = wKs[j]; dsc.N[j] = wNs[j]; dsc.start[j] = wStart[j];
      dsc.lstride[j] = wLstr[j];
    }
    dsc.start[9] = wStart[9];
    wconv_kernel<<<480 * L_, 256, 0, stream>>>(dsc, Wb4);
  }
  // layer-0 ln1 reads H_in directly and materializes the H state copy
  ln_kernel<<<ROWS, 256, 0, stream>>>(H_in, ln1g, ln1b, Hnb, Hs);

  for (int l = 0; l < L_; ++l) {
    us* Wb = Wb4 + (size_t)l * 1966080u;

    // fused QKV GEMM + Vvv GEMM + bias precombine in one dispatch
    gemm_qkv<<<dim3(36, 66), 256, 0, stream>>>(
        Hnb, Wb + wOff[0], bq + l * 1024, bk + l * 1024, bv + l * 256,
        QKVb, rbf + (size_t)l * B_ * N_ * N_, Db, bias_b, FACTOR_ * LOG2E_,
        Vb, Wb + wOff[3], Vvb);
    pack_vattn_t<<<512, 256, 0, stream>>>(QKVb, Vvb, Vtb);
    attn_mfma<<<1024, 256, 0, stream>>>(QKVb, Vtb, bias_b, Opart, Mlp);
    attn_combine<<<ROWS, 256, 0, stream>>>(Opart, Mlp, Hres_b, Vres_b);
    gemm_wo<<<dim3(4, 256), 256, 0, stream>>>(
        Hres_b, Vres_b, Wb + wOff[4], Wb + wOff[5], bo + l * 256, Hs, Vs, Vb);
    gemm_v2<128,64,0,0,0,1,0,0,3><<<dim3(8, 96), 256, 0, stream>>>(
        Vb, Wb + wOff[6], nullptr, nullptr, nullptr, Vp, nullptr, 12288, 256, 512, 1.f);
    ln2scaler<<<ROWS, 256, 0, stream>>>(Hs, ln2g + l * D_, ln2b + l * D_, Vp, scal_b);
    gemm_v2<128,64,1,0,1,0,1,0,3><<<dim3(16, 32), 256, 0, stream>>>(
        scal_b, Wb + wOff[7], b1 + l * 1024, nullptr, nullptr, nullptr, midb, 4096, 512, 1024, 1.f);
    gemm_w2<<<dim3(8, 64), 256, 0, stream>>>(
        midb, Wb + wOff[8], b2 + l * 512, Vp, Hs, Vs, Vb);
    if (l < 3)
      ln_kernel<<<ROWS, 256, 0, stream>>>(Hs, ln1g + (l + 1) * D_,
                                          ln1b + (l + 1) * D_, Hnb, nullptr);
  }
}

// Round 29
// 745.095 us; speedup vs baseline: 1.1167x; 1.1167x over previous
//
#include <hip/hip_runtime.h>
#include <math.h>

static constexpr int B_  = 2;
static constexpr int N_  = 2048;
static constexpr int D_  = 256;
static constexpr int NH_ = 8;
static constexpr int L_  = 4;
static constexpr int DH_ = 32;
static constexpr int DQ_ = 128;   // 4*DH
static constexpr float FACTOR_ = 0.08838834764831845f;  // 0.5/sqrt(32)
static constexpr float LOG2E_  = 1.4426950408889634f;
static constexpr float EPS_ = 1e-5f;

typedef short    short8   __attribute__((ext_vector_type(8)));
typedef unsigned short us4 __attribute__((ext_vector_type(4)));
typedef unsigned short us8 __attribute__((ext_vector_type(8)));
typedef float    f32x4    __attribute__((ext_vector_type(4)));
typedef unsigned short us;

__device__ __forceinline__ us f2b(float f) {
  unsigned u = __float_as_uint(f);
  unsigned r = u + 0x7FFF + ((u >> 16) & 1);
  return (us)(r >> 16);
}
__device__ __forceinline__ float b2f(us u) {
  return __uint_as_float(((unsigned)u) << 16);
}
__device__ __forceinline__ float e2(float x) {
  return __builtin_amdgcn_exp2f(x);
}
__device__ __forceinline__ void gl_lds16(const void* g, void* l) {
  __builtin_amdgcn_global_load_lds(
      (const __attribute__((address_space(1))) void*)g,
      (__attribute__((address_space(3))) void*)l, 16, 0, 0);
}

// ---------------- LayerNorm: shuffle reduce, writes bf16 (+opt state copy) ---
__global__ __launch_bounds__(256) void ln_kernel(const float* __restrict__ X,
    const float* __restrict__ g, const float* __restrict__ b,
    us* __restrict__ Y, float* __restrict__ Xcopy) {
  __shared__ float p1[4], p2[4];
  int row = blockIdx.x, tid = threadIdx.x;
  float x = X[(size_t)row * D_ + tid];
  if (Xcopy) Xcopy[(size_t)row * D_ + tid] = x;
  float a = x, c = x * x;
  #pragma unroll
  for (int o = 32; o > 0; o >>= 1) {
    a += __shfl_xor(a, o, 64);
    c += __shfl_xor(c, o, 64);
  }
  if ((tid & 63) == 0) { p1[tid >> 6] = a; p2[tid >> 6] = c; }
  __syncthreads();
  float s1 = (p1[0] + p1[1]) + (p1[2] + p1[3]);
  float s2 = (p2[0] + p2[1]) + (p2[2] + p2[3]);
  float mean = s1 * (1.0f / D_);
  float var  = s2 * (1.0f / D_) - mean * mean;
  float inv  = rsqrtf(var + EPS_);
  Y[(size_t)row * D_ + tid] = f2b((x - mean) * inv * g[tid] + b[tid]);
}

// ---------------- V init: copy f32 state + bf16 mirror, 4 elems/thread ------
__global__ __launch_bounds__(256) void conv_copy(const float* __restrict__ X,
    float* __restrict__ Yf, us* __restrict__ Y) {
  size_t i = ((size_t)blockIdx.x * 256 + threadIdx.x) * 4;
  float4 v = *(const float4*)&X[i];
  *(float4*)&Yf[i] = v;
  us4 o = { f2b(v.x), f2b(v.y), f2b(v.z), f2b(v.w) };
  *(us4*)&Y[i] = o;
}

// ---------------- weight convert + transpose, ALL LAYERS ---------------------
struct WConvDesc {
  const float* src[9];
  unsigned dst[9];
  int K[9];
  int N[9];
  int start[10];
  int lstride[9];
};
__global__ __launch_bounds__(256) void wconv_kernel(WConvDesc d, us* __restrict__ Wb) {
  __shared__ float T[64][65];
  int bid0 = blockIdx.x, tid = threadIdx.x;
  int lay = bid0 / 480;
  int bid = bid0 - lay * 480;
  int j = 0;
  #pragma unroll
  for (int q = 0; q < 8; q++) if (bid >= d.start[q + 1]) j = q + 1;
  int t = bid - d.start[j];
  int K = d.K[j], N = d.N[j];
  int tpr = N >> 6;
  int tk = t / tpr, tn = t - tk * tpr;
  const float* src = d.src[j] + (size_t)lay * d.lstride[j];
  us* dst = Wb + (size_t)lay * 1966080u + d.dst[j];
  #pragma unroll
  for (int i = 0; i < 4; i++) {
    int r = i * 16 + (tid >> 4), c = (tid & 15) * 4;
    *(float4*)&T[r][c] = *(const float4*)&src[(size_t)(tk * 64 + r) * N + tn * 64 + c];
  }
  __syncthreads();
  #pragma unroll
  for (int i = 0; i < 4; i++) {
    int n = i * 16 + (tid >> 4), k = (tid & 15) * 4;
    us4 o = { f2b(T[k][n]), f2b(T[k + 1][n]), f2b(T[k + 2][n]), f2b(T[k + 3][n]) };
    *(us4*)&dst[(size_t)(tn * 64 + n) * K + tk * 64 + k] = o;
  }
}

// ---------------- QKV GEMM + Vvv GEMM + bias precombine, one dispatch --------
// grid (36, 66): by<32 -> 128x64 QKV tile; 32<=by<54 -> 64x64 Vvv tile
// (linear id, 768 active); by>=54 -> grid-stride biascomb (tail filler).
__global__ __launch_bounds__(256, 3) void gemm_qkv(const us* __restrict__ A,
    const us* __restrict__ Wt, const float* __restrict__ bias,
    const float* __restrict__ bias2, const float* __restrict__ bias3,
    us* __restrict__ Cb, const float* __restrict__ R,
    const float* __restrict__ Dq, us* __restrict__ BiasOut, float oscale,
    const us* __restrict__ Vbm, const us* __restrict__ WtVV,
    us* __restrict__ Vvb) {
  constexpr int BM = 128, BN = 64, K = 256, Nc = 2304;
  __shared__ us As[2][BM * 64];
  __shared__ us Bs[2][BN * 64];
  const int tid = threadIdx.x;

  if (blockIdx.y >= 54) {            // ---- bias precombine path ----
    const size_t total = (size_t)B_ * N_ * N_;
    const int nb = (gridDim.y - 54) * gridDim.x;
    const int bidl = (blockIdx.y - 54) * gridDim.x + blockIdx.x;
    const size_t step = (size_t)nb * 256 * 8;
    for (size_t i = ((size_t)bidl * 256 + tid) * 8; i < total; i += step) {
      float4 r0 = *(const float4*)&R[i];
      float4 r1 = *(const float4*)&R[i + 4];
      float4 d0 = *(const float4*)&Dq[i];
      float4 d1 = *(const float4*)&Dq[i + 4];
      us8 o = { f2b((r0.x + d0.x) * LOG2E_), f2b((r0.y + d0.y) * LOG2E_),
                f2b((r0.z + d0.z) * LOG2E_), f2b((r0.w + d0.w) * LOG2E_),
                f2b((r1.x + d1.x) * LOG2E_), f2b((r1.y + d1.y) * LOG2E_),
                f2b((r1.z + d1.z) * LOG2E_), f2b((r1.w + d1.w) * LOG2E_) };
      *(us8*)&BiasOut[i] = o;
    }
    return;
  }

  const int w = tid >> 6, l = tid & 63;
  const int lx = l & 15, ly = l >> 4;
  const int wr = w >> 1, wc = w & 1;
  const int swz = (lx & 7) << 4;
  const size_t rowb = (size_t)K * 2;

  if (blockIdx.y >= 32) {            // ---- Vvv 64x64 GEMM path ----
    const int q = (blockIdx.y - 32) * 36 + blockIdx.x;
    if (q >= 768) return;
    const int bn = q & 3, bm = q >> 2;
    const char* Ag = (const char*)Vbm + (size_t)(bm * 64) * K * 2;
    const char* Bg = (const char*)WtVV + (size_t)(bn * 64) * K * 2;

    #define GSTAGE2(buf, k0)                                                  \
      do {                                                                    \
        _Pragma("unroll")                                                     \
        for (int j = 0; j < 2; j++) {                                         \
          int o = j * 4096 + tid * 16;                                        \
          int r = o >> 7, cb = o & 127;                                       \
          int sc = cb ^ ((r & 7) << 4);                                       \
          gl_lds16(Ag + (size_t)r * rowb + (size_t)(k0) * 2 + sc,             \
                   &As[buf][(j * 4096 + w * 1024) >> 1]);                     \
          gl_lds16(Bg + (size_t)r * rowb + (size_t)(k0) * 2 + sc,             \
                   &Bs[buf][(j * 4096 + w * 1024) >> 1]);                     \
        }                                                                     \
      } while (0)

    f32x4 acc[2][2];
    #pragma unroll
    for (int i = 0; i < 2; i++)
      #pragma unroll
      for (int j = 0; j < 2; j++) acc[i][j] = (f32x4){0.f, 0.f, 0.f, 0.f};

    int cur = 0;
    GSTAGE2(0, 0);
    __syncthreads();
    for (int k0 = 0; k0 < K; k0 += 64) {
      if (k0 + 64 < K) GSTAGE2(cur ^ 1, k0 + 64);
      #pragma unroll
      for (int s = 0; s < 2; s++) {
        short8 af[2], bf[2];
        #pragma unroll
        for (int mt = 0; mt < 2; mt++)
          af[mt] = *(const short8*)
              &As[cur][(((wr * 32 + mt * 16 + lx) * 128) + ((s * 64 + ly * 16) ^ swz)) >> 1];
        #pragma unroll
        for (int nt = 0; nt < 2; nt++)
          bf[nt] = *(const short8*)
              &Bs[cur][(((wc * 32 + nt * 16 + lx) * 128) + ((s * 64 + ly * 16) ^ swz)) >> 1];
        __builtin_amdgcn_s_setprio(1);
        #pragma unroll
        for (int mt = 0; mt < 2; mt++)
          #pragma unroll
          for (int nt = 0; nt < 2; nt++)
            acc[mt][nt] = __builtin_amdgcn_mfma_f32_16x16x32_bf16(af[mt], bf[nt], acc[mt][nt], 0, 0, 0);
        __builtin_amdgcn_s_setprio(0);
      }
      __syncthreads();
      cur ^= 1;
    }
    #undef GSTAGE2

    #pragma unroll
    for (int nt = 0; nt < 2; nt++) {
      const int n = bn * 64 + wc * 32 + nt * 16 + lx;
      #pragma unroll
      for (int mt = 0; mt < 2; mt++) {
        #pragma unroll
        for (int r = 0; r < 4; r++) {
          const int m = bm * 64 + wr * 32 + mt * 16 + ly * 4 + r;
          Vvb[(size_t)m * 256 + n] = f2b(acc[mt][nt][r]);
        }
      }
    }
    return;
  }

  // ---- QKV 128x64 GEMM path ----
  const int bn = blockIdx.x, bm = blockIdx.y;
  const char* Ag = (const char*)A + (size_t)(bm * BM) * K * 2;
  const char* Bg = (const char*)Wt + (size_t)(bn * BN) * K * 2;

  #define GSTAGE(buf, k0)                                                     \
    do {                                                                      \
      _Pragma("unroll")                                                       \
      for (int j = 0; j < 4; j++) {                                           \
        int o = j * 4096 + tid * 16;                                          \
        int r = o >> 7, cb = o & 127;                                         \
        int sc = cb ^ ((r & 7) << 4);                                         \
        gl_lds16(Ag + (size_t)r * rowb + (size_t)(k0) * 2 + sc,               \
                 &As[buf][(j * 4096 + w * 1024) >> 1]);                       \
      }                                                                       \
      _Pragma("unroll")                                                       \
      for (int j = 0; j < 2; j++) {                                           \
        int o = j * 4096 + tid * 16;                                          \
        int r = o >> 7, cb = o & 127;                                         \
        int sc = cb ^ ((r & 7) << 4);                                         \
        gl_lds16(Bg + (size_t)r * rowb + (size_t)(k0) * 2 + sc,               \
                 &Bs[buf][(j * 4096 + w * 1024) >> 1]);                       \
      }                                                                       \
    } while (0)

  f32x4 acc[4][2];
  #pragma unroll
  for (int i = 0; i < 4; i++)
    #pragma unroll
    for (int j = 0; j < 2; j++) acc[i][j] = (f32x4){0.f, 0.f, 0.f, 0.f};

  int cur = 0;
  GSTAGE(0, 0);
  __syncthreads();
  for (int k0 = 0; k0 < K; k0 += 64) {
    if (k0 + 64 < K) GSTAGE(cur ^ 1, k0 + 64);
    #pragma unroll
    for (int s = 0; s < 2; s++) {
      short8 af[4], bf[2];
      #pragma unroll
      for (int mt = 0; mt < 4; mt++)
        af[mt] = *(const short8*)
            &As[cur][(((wr * 64 + mt * 16 + lx) * 128) + ((s * 64 + ly * 16) ^ swz)) >> 1];
      #pragma unroll
      for (int nt = 0; nt < 2; nt++)
        bf[nt] = *(const short8*)
            &Bs[cur][(((wc * 32 + nt * 16 + lx) * 128) + ((s * 64 + ly * 16) ^ swz)) >> 1];
      __builtin_amdgcn_s_setprio(1);
      #pragma unroll
      for (int mt = 0; mt < 4; mt++)
        #pragma unroll
        for (int nt = 0; nt < 2; nt++)
          acc[mt][nt] = __builtin_amdgcn_mfma_f32_16x16x32_bf16(af[mt], bf[nt], acc[mt][nt], 0, 0, 0);
      __builtin_amdgcn_s_setprio(0);
    }
    __syncthreads();
    cur ^= 1;
  }
  #undef GSTAGE

  #pragma unroll
  for (int nt = 0; nt < 2; nt++) {
    const int n = bn * BN + wc * 32 + nt * 16 + lx;
    float bval, osc = oscale;
    if (n < 1024)      { bval = bias[n]; }
    else if (n < 2048) { bval = bias2[n - 1024]; osc = 1.0f; }
    else               { bval = bias3[n - 2048]; osc = 1.0f; }
    #pragma unroll
    for (int mt = 0; mt < 4; mt++) {
      #pragma unroll
      for (int r = 0; r < 4; r++) {
        const int m = bm * BM + wr * 64 + mt * 16 + ly * 4 + r;
        float v = acc[mt][nt][r] + bval;
        Cb[(size_t)m * Nc + n] = f2b(v * osc);
      }
    }
  }
}

// ---------------- gemm_v2: asymmetric BM x BN tiles, gl_lds dbuf -------------
template<int BM, int BN, int BIAS, int ACC, int SILU, int WF, int WB, int QKV, int MINW>
__global__ __launch_bounds__(256, MINW) void gemm_v2(const us* __restrict__ A,
    const us* __restrict__ Wt, const float* __restrict__ bias,
    const float* __restrict__ bias2, const float* __restrict__ bias3,
    float* __restrict__ Cf, us* __restrict__ Cb,
    int M, int K, int Nc, float oscale) {
  constexpr int NFM = BM / 32, NFN = BN / 32;
  constexpr int WSM = NFM * 16, WSN = NFN * 16;
  constexpr int NLA = BM / 32, NLB = BN / 32;
  __shared__ us As[2][BM * 64];
  __shared__ us Bs[2][BN * 64];
  const int tid = threadIdx.x;
  const int w = tid >> 6, l = tid & 63;
  const int lx = l & 15, ly = l >> 4;
  const int wr = w >> 1, wc = w & 1;
  const int bn = blockIdx.x, bm = blockIdx.y;
  const int swz = (lx & 7) << 4;
  const char* Ag = (const char*)A + (size_t)(bm * BM) * K * 2;
  const char* Bg = (const char*)Wt + (size_t)(bn * BN) * K * 2;
  const size_t rowb = (size_t)K * 2;

  #define GSTAGE(buf, k0)                                                     \
    do {                                                                      \
      _Pragma("unroll")                                                       \
      for (int j = 0; j < NLA; j++) {                                         \
        int o = j * 4096 + tid * 16;                                          \
        int r = o >> 7, cb = o & 127;                                         \
        int sc = cb ^ ((r & 7) << 4);                                         \
        gl_lds16(Ag + (size_t)r * rowb + (size_t)(k0) * 2 + sc,               \
                 &As[buf][(j * 4096 + w * 1024) >> 1]);                       \
      }                                                                       \
      _Pragma("unroll")                                                       \
      for (int j = 0; j < NLB; j++) {                                         \
        int o = j * 4096 + tid * 16;                                          \
        int r = o >> 7, cb = o & 127;                                         \
        int sc = cb ^ ((r & 7) << 4);                                         \
        gl_lds16(Bg + (size_t)r * rowb + (size_t)(k0) * 2 + sc,               \
                 &Bs[buf][(j * 4096 + w * 1024) >> 1]);                       \
      }                                                                       \
    } while (0)

  f32x4 acc[NFM][NFN];
  #pragma unroll
  for (int i = 0; i < NFM; i++)
    #pragma unroll
    for (int j = 0; j < NFN; j++) acc[i][j] = (f32x4){0.f, 0.f, 0.f, 0.f};

  int cur = 0;
  GSTAGE(0, 0);
  __syncthreads();
  for (int k0 = 0; k0 < K; k0 += 64) {
    if (k0 + 64 < K) GSTAGE(cur ^ 1, k0 + 64);
    #pragma unroll
    for (int s = 0; s < 2; s++) {
      short8 af[NFM], bf[NFN];
      #pragma unroll
      for (int mt = 0; mt < NFM; mt++)
        af[mt] = *(const short8*)
            &As[cur][(((wr * WSM + mt * 16 + lx) * 128) + ((s * 64 + ly * 16) ^ swz)) >> 1];
      #pragma unroll
      for (int nt = 0; nt < NFN; nt++)
        bf[nt] = *(const short8*)
            &Bs[cur][(((wc * WSN + nt * 16 + lx) * 128) + ((s * 64 + ly * 16) ^ swz)) >> 1];
      __builtin_amdgcn_s_setprio(1);
      #pragma unroll
      for (int mt = 0; mt < NFM; mt++)
        #pragma unroll
        for (int nt = 0; nt < NFN; nt++)
          acc[mt][nt] = __builtin_amdgcn_mfma_f32_16x16x32_bf16(af[mt], bf[nt], acc[mt][nt], 0, 0, 0);
      __builtin_amdgcn_s_setprio(0);
    }
    __syncthreads();
    cur ^= 1;
  }
  #undef GSTAGE

  #pragma unroll
  for (int nt = 0; nt < NFN; nt++) {
    const int n = bn * BN + wc * WSN + nt * 16 + lx;
    float bval = 0.f, osc = oscale;
    if (QKV) {
      if (n < 1024)      { bval = bias[n]; }
      else if (n < 2048) { bval = bias2[n - 1024]; osc = 1.0f; }
      else               { bval = bias3[n - 2048]; osc = 1.0f; }
    } else if (BIAS) {
      bval = bias[n];
    }
    #pragma unroll
    for (int mt = 0; mt < NFM; mt++) {
      #pragma unroll
      for (int r = 0; r < 4; r++) {
        const int m = bm * BM + wr * WSM + mt * 16 + ly * 4 + r;
        float v = acc[mt][nt][r] + bval;
        if (SILU) v = v / (1.f + __expf(-v));
        size_t idx = (size_t)m * Nc + n;
        if (ACC) v += Cf[idx];
        if (WF) Cf[idx] = v;
        if (WB) Cb[idx] = f2b(v * osc);
      }
    }
  }
}

// ---------------- merged Wo+Wvo GEMM: H path (bm<64) + V path ----------------
__global__ __launch_bounds__(256, 3) void gemm_wo(const us* __restrict__ Hres,
    const us* __restrict__ Vres, const us* __restrict__ WtO,
    const us* __restrict__ WtVO, const float* __restrict__ bo,
    float* __restrict__ Hs, float* __restrict__ Vs, us* __restrict__ Vb) {
  constexpr int K = 256, Nc = 256;
  __shared__ us As[2][64 * 64];
  __shared__ us Bs[2][64 * 64];
  const int tid = threadIdx.x;
  const int w = tid >> 6, l = tid & 63;
  const int lx = l & 15, ly = l >> 4;
  const int wr = w >> 1, wc = w & 1;
  const int bn = blockIdx.x, bm = blockIdx.y;
  const bool isH = bm < 64;
  const int mb = isH ? bm : bm - 64;
  const int swz = (lx & 7) << 4;
  const char* Ag = (const char*)(isH ? Hres : Vres) + (size_t)(mb * 64) * K * 2;
  const char* Bg = (const char*)(isH ? WtO : WtVO) + (size_t)(bn * 64) * K * 2;
  const size_t rowb = (size_t)K * 2;

  #define GSTAGE(buf, k0)                                                     \
    do {                                                                      \
      _Pragma("unroll")                                                       \
      for (int j = 0; j < 2; j++) {                                           \
        int o = j * 4096 + tid * 16;                                          \
        int r = o >> 7, cb = o & 127;                                         \
        int sc = cb ^ ((r & 7) << 4);                                         \
        gl_lds16(Ag + (size_t)r * rowb + (size_t)(k0) * 2 + sc,               \
                 &As[buf][(j * 4096 + w * 1024) >> 1]);                       \
        gl_lds16(Bg + (size_t)r * rowb + (size_t)(k0) * 2 + sc,               \
                 &Bs[buf][(j * 4096 + w * 1024) >> 1]);                       \
      }                                                                       \
    } while (0)

  f32x4 acc[2][2];
  #pragma unroll
  for (int i = 0; i < 2; i++)
    #pragma unroll
    for (int j = 0; j < 2; j++) acc[i][j] = (f32x4){0.f, 0.f, 0.f, 0.f};

  int cur = 0;
  GSTAGE(0, 0);
  __syncthreads();
  for (int k0 = 0; k0 < K; k0 += 64) {
    if (k0 + 64 < K) GSTAGE(cur ^ 1, k0 + 64);
    #pragma unroll
    for (int s = 0; s < 2; s++) {
      short8 af[2], bf[2];
      #pragma unroll
      for (int mt = 0; mt < 2; mt++)
        af[mt] = *(const short8*)
            &As[cur][(((wr * 32 + mt * 16 + lx) * 128) + ((s * 64 + ly * 16) ^ swz)) >> 1];
      #pragma unroll
      for (int nt = 0; nt < 2; nt++)
        bf[nt] = *(const short8*)
            &Bs[cur][(((wc * 32 + nt * 16 + lx) * 128) + ((s * 64 + ly * 16) ^ swz)) >> 1];
      __builtin_amdgcn_s_setprio(1);
      #pragma unroll
      for (int mt = 0; mt < 2; mt++)
        #pragma unroll
        for (int nt = 0; nt < 2; nt++)
          acc[mt][nt] = __builtin_amdgcn_mfma_f32_16x16x32_bf16(af[mt], bf[nt], acc[mt][nt], 0, 0, 0);
      __builtin_amdgcn_s_setprio(0);
    }
    __syncthreads();
    cur ^= 1;
  }
  #undef GSTAGE

  #pragma unroll
  for (int nt = 0; nt < 2; nt++) {
    const int n = bn * 64 + wc * 32 + nt * 16 + lx;
    const float bval = isH ? bo[n] : 0.f;
    #pragma unroll
    for (int mt = 0; mt < 2; mt++) {
      #pragma unroll
      for (int r = 0; r < 4; r++) {
        const int m = mb * 64 + wr * 32 + mt * 16 + ly * 4 + r;
        size_t idx = (size_t)m * Nc + n;
        float v = acc[mt][nt][r] + bval;
        if (isH) {
          Hs[idx] += v;
        } else {
          float nv = Vs[idx] + v;
          Vs[idx] = nv;
          Vb[idx] = f2b(nv);
        }
      }
    }
  }
}

// ---------------- W2 GEMM with fused final H/V update ------------------------
__global__ __launch_bounds__(256, 3) void gemm_w2(const us* __restrict__ A,
    const us* __restrict__ Wt, const float* __restrict__ b2,
    const float* __restrict__ Vp, float* __restrict__ Hs,
    float* __restrict__ Vs, us* __restrict__ Vb) {
  constexpr int K = 1024;
  __shared__ us As[2][64 * 64];
  __shared__ us Bs[2][64 * 64];
  const int tid = threadIdx.x;
  const int w = tid >> 6, l = tid & 63;
  const int lx = l & 15, ly = l >> 4;
  const int wr = w >> 1, wc = w & 1;
  const int bn = blockIdx.x, bm = blockIdx.y;
  const int swz = (lx & 7) << 4;
  const char* Ag = (const char*)A + (size_t)(bm * 64) * K * 2;
  const char* Bg = (const char*)Wt + (size_t)(bn * 64) * K * 2;
  const size_t rowb = (size_t)K * 2;

  #define GSTAGE(buf, k0)                                                     \
    do {                                                                      \
      _Pragma("unroll")                                                       \
      for (int j = 0; j < 2; j++) {                                           \
        int o = j * 4096 + tid * 16;                                          \
        int r = o >> 7, cb = o & 127;                                         \
        int sc = cb ^ ((r & 7) << 4);                                         \
        gl_lds16(Ag + (size_t)r * rowb + (size_t)(k0) * 2 + sc,               \
                 &As[buf][(j * 4096 + w * 1024) >> 1]);                       \
        gl_lds16(Bg + (size_t)r * rowb + (size_t)(k0) * 2 + sc,               \
                 &Bs[buf][(j * 4096 + w * 1024) >> 1]);                       \
      }                                                                      \
    } while (0)

  f32x4 acc[2][2];
  #pragma unroll
  for (int i = 0; i < 2; i++)
    #pragma unroll
    for (int j = 0; j < 2; j++) acc[i][j] = (f32x4){0.f, 0.f, 0.f, 0.f};

  int cur = 0;
  GSTAGE(0, 0);
  __syncthreads();
  for (int k0 = 0; k0 < K; k0 += 64) {
    if (k0 + 64 < K) GSTAGE(cur ^ 1, k0 + 64);
    #pragma unroll
    for (int s = 0; s < 2; s++) {
      short8 af[2], bf[2];
      #pragma unroll
      for (int mt = 0; mt < 2; mt++)
        af[mt] = *(const short8*)
            &As[cur][(((wr * 32 + mt * 16 + lx) * 128) + ((s * 64 + ly * 16) ^ swz)) >> 1];
      #pragma unroll
      for (int nt = 0; nt < 2; nt++)
        bf[nt] = *(const short8*)
            &Bs[cur][(((wc * 32 + nt * 16 + lx) * 128) + ((s * 64 + ly * 16) ^ swz)) >> 1];
      __builtin_amdgcn_s_setprio(1);
      #pragma unroll
      for (int mt = 0; mt < 2; mt++)
        #pragma unroll
        for (int nt = 0; nt < 2; nt++)
          acc[mt][nt] = __builtin_amdgcn_mfma_f32_16x16x32_bf16(af[mt], bf[nt], acc[mt][nt], 0, 0, 0);
      __builtin_amdgcn_s_setprio(0);
    }
    __syncthreads();
    cur ^= 1;
  }
  #undef GSTAGE

  const bool isH = (bn < 4);
  #pragma unroll
  for (int nt = 0; nt < 2; nt++) {
    const int n = bn * 64 + wc * 32 + nt * 16 + lx;
    const float bval = b2[n];
    #pragma unroll
    for (int mt = 0; mt < 2; mt++) {
      #pragma unroll
      for (int r = 0; r < 4; r++) {
        const int m = bm * 64 + wr * 32 + mt * 16 + ly * 4 + r;
        float v = acc[mt][nt][r] + bval;
        if (isH) {
          Hs[(size_t)m * D_ + n] += v;
        } else {
          const int j = n - 256;
          #pragma unroll
          for (int c = 0; c < 3; c++) {
            size_t vi = ((size_t)m * 3 + c) * D_ + j;
            float nv = Vs[vi] + v * Vp[((size_t)m * 3 + c) * 512 + 256 + j];
            Vs[vi] = nv;
            Vb[vi] = f2b(nv);
          }
        }
      }
    }
  }
}

// ---------------- pack V_attn transposed: Vt[b][h][128][N] bf16 --------------
__global__ __launch_bounds__(256) void pack_vattn_t(const us* __restrict__ QKVb,
    const us* __restrict__ Vv, us* __restrict__ Vt) {
  __shared__ us T[64][136];
  const int bid = blockIdx.x;
  const int nt = bid & 31, hh = (bid >> 5) & 7, b = bid >> 8;
  const int n0 = nt * 64;
  const int tid = threadIdx.x;
  {
    const int nn = tid >> 2, part = tid & 3;
    const size_t row = (size_t)(b * N_ + n0 + nn);
    const us* src = (part == 0) ? (QKVb + row * 2304 + 2048 + hh * DH_)
                                : (Vv + (row * 3 + (part - 1)) * D_ + hh * DH_);
    #pragma unroll
    for (int jj = 0; jj < 32; jj += 8)
      *(us8*)&T[nn][part * 32 + jj] = *(const us8*)(src + jj);
  }
  __syncthreads();
  const int d = tid >> 1, half = tid & 1;
  size_t ob = ((size_t)(b * NH_ + hh) * DQ_ + d) * (size_t)N_ + n0 + half * 32;
  #pragma unroll
  for (int i = 0; i < 32; i += 8) {
    us8 o;
    #pragma unroll
    for (int e = 0; e < 8; e++) o[e] = T[half * 32 + i + e][d];
    *(us8*)&Vt[ob + i] = o;
  }
}

// ---------------- MFMA flash attention: single-buf LDS, reg prefetch ---------
__global__ __launch_bounds__(256, 3) void attn_mfma(
    const us* __restrict__ QKVb,     // [B*N][2304]: Q(FACTOR*log2e) | K | Hv
    const us* __restrict__ Vtb,      // [B][NH][128][N]
    const us* __restrict__ bias,     // layer slice [B][N][N] bf16
    us* __restrict__ Hres,           // [B*N][256] bf16
    us* __restrict__ Vres) {         // [B*N][3][256] bf16
  __shared__ us Kt[8192];            // 16KB: [64 m-rows][256B]
  __shared__ us Vt[8192];            // 16KB: [128 d-rows][128B]
  __shared__ us Plds[4][16][72];     // 9KB
  const int bid = blockIdx.x;
  const int h  = bid & 7;
  const int g  = bid >> 3;
  const int b  = g >> 5;
  const int qt = g & 31;
  const int tid = threadIdx.x;
  const int w  = tid >> 6;
  const int l  = tid & 63;
  const int lx = l & 15;
  const int ly = l >> 4;
  const int qrow = qt * 64 + w * 16 + lx;
  const int swz = (lx & 7) << 4;

  short8 qf[4];
  {
    const us* qp = QKVb + (size_t)(b * N_ + qrow) * 2304 + h * DQ_ + ly * 8;
    #pragma unroll
    for (int s = 0; s < 4; s++) qf[s] = *(const short8*)(qp + s * 32);
  }
  const char* kg = (const char*)QKVb + (size_t)b * N_ * 4608 + 2048 + h * 256;
  const char* vg = (const char*)(Vtb + ((size_t)(b * NH_ + h) * DQ_) * (size_t)N_);
  const us* bbase = bias + ((size_t)b * N_ + qrow) * N_;

  us8 kreg[4], vreg[4];
  #define LOADKV(m0)                                                          \
    do {                                                                      \
      _Pragma("unroll")                                                       \
      for (int j = 0; j < 4; j++) {                                           \
        int o = j * 4096 + tid * 16;                                          \
        int rk = o >> 8, ck = o & 255;                                        \
        kreg[j] = *(const us8*)(kg + (size_t)((m0) + rk) * 4608 +             \
                                (ck ^ ((rk & 7) << 4)));                      \
        int rv = o >> 7, cv = o & 127;                                        \
        vreg[j] = *(const us8*)(vg + (size_t)rv * (N_ * 2) +                  \
                                (size_t)(m0) * 2 + (cv ^ ((rv & 7) << 4)));   \
      }                                                                       \
    } while (0)
  #define WRITEKV()                                                           \
    do {                                                                      \
      _Pragma("unroll")                                                       \
      for (int j = 0; j < 4; j++) {                                           \
        *(us8*)&Kt[j * 2048 + tid * 8] = kreg[j];                             \
        *(us8*)&Vt[j * 2048 + tid * 8] = vreg[j];                             \
      }                                                                       \
    } while (0)

  float m_run = -3.0e38f, l_run = 0.f;   // l_run: per-lane partial
  f32x4 oacc[8];
  #pragma unroll
  for (int i = 0; i < 8; i++) oacc[i] = (f32x4){0.f, 0.f, 0.f, 0.f};

  LOADKV(0);
  WRITEKV();                 // compiler inserts vmcnt wait before ds_write
  LOADKV(64);                // prefetch chunk 1 into regs
  us4 bb[4];
  #pragma unroll
  for (int t = 0; t < 4; t++) bb[t] = *(const us4*)(bbase + t * 16 + ly * 4);
  __syncthreads();

  for (int mc0 = 0; mc0 < N_; mc0 += 64) {
    us4 bbn[4];
    if (mc0 + 64 < N_) {
      #pragma unroll
      for (int t = 0; t < 4; t++)
        bbn[t] = *(const us4*)(bbase + mc0 + 64 + t * 16 + ly * 4);
    }
    f32x4 sacc[4];
    #pragma unroll
    for (int t = 0; t < 4; t++) sacc[t] = (f32x4){0.f, 0.f, 0.f, 0.f};
    __builtin_amdgcn_s_setprio(1);
    #pragma unroll
    for (int t = 0; t < 4; t++) {
      #pragma unroll
      for (int s = 0; s < 4; s++) {
        const short8 kf = *(const short8*)
            &Kt[((t * 16 + lx) * 256 + ((s * 64 + ly * 16) ^ swz)) >> 1];
        sacc[t] = __builtin_amdgcn_mfma_f32_16x16x32_bf16(kf, qf[s], sacc[t], 0, 0, 0);
      }
    }
    __builtin_amdgcn_s_setprio(0);
    float pvv[16];
    #pragma unroll
    for (int t = 0; t < 4; t++) {
      pvv[t*4+0] = sacc[t][0] + b2f(bb[t][0]);
      pvv[t*4+1] = sacc[t][1] + b2f(bb[t][1]);
      pvv[t*4+2] = sacc[t][2] + b2f(bb[t][2]);
      pvv[t*4+3] = sacc[t][3] + b2f(bb[t][3]);
    }
    float a8[8], a4[4];
    #pragma unroll
    for (int i = 0; i < 8; i++) a8[i] = fmaxf(pvv[i], pvv[i + 8]);
    #pragma unroll
    for (int i = 0; i < 4; i++) a4[i] = fmaxf(a8[i], a8[i + 4]);
    float mloc = fmaxf(fmaxf(a4[0], a4[1]), fmaxf(a4[2], a4[3]));
    if (!__all(mloc - m_run <= 11.54f)) {
      mloc = fmaxf(mloc, __shfl_xor(mloc, 16, 64));
      mloc = fmaxf(mloc, __shfl_xor(mloc, 32, 64));
      float m_new = fmaxf(m_run, mloc);
      float scale = e2(m_run - m_new);
      l_run *= scale;
      #pragma unroll
      for (int i = 0; i < 8; i++) {
        oacc[i][0] *= scale; oacc[i][1] *= scale;
        oacc[i][2] *= scale; oacc[i][3] *= scale;
      }
      m_run = m_new;
    }
    float s8[8], s4[4];
    #pragma unroll
    for (int i = 0; i < 16; i++) pvv[i] = e2(pvv[i] - m_run);
    #pragma unroll
    for (int i = 0; i < 8; i++) s8[i] = pvv[i] + pvv[i + 8];
    #pragma unroll
    for (int i = 0; i < 4; i++) s4[i] = s8[i] + s8[i + 4];
    l_run += (s4[0] + s4[1]) + (s4[2] + s4[3]);
    #pragma unroll
    for (int t = 0; t < 4; t++) {
      us4 pk = { f2b(pvv[t*4+0]), f2b(pvv[t*4+1]), f2b(pvv[t*4+2]), f2b(pvv[t*4+3]) };
      *(us4*)&Plds[w][lx][t * 16 + ly * 4] = pk;
    }
    short8 pf0 = *(const short8*)&Plds[w][lx][ly * 8];
    short8 pf1 = *(const short8*)&Plds[w][lx][32 + ly * 8];
    __builtin_amdgcn_s_setprio(1);
    #pragma unroll
    for (int dt = 0; dt < 8; dt++) {
      const int rb = (dt * 16 + lx) * 128;
      const short8 vf0 = *(const short8*)&Vt[(rb + ((ly * 16) ^ swz)) >> 1];
      const short8 vf1 = *(const short8*)&Vt[(rb + ((64 + ly * 16) ^ swz)) >> 1];
      oacc[dt] = __builtin_amdgcn_mfma_f32_16x16x32_bf16(vf0, pf0, oacc[dt], 0, 0, 0);
      oacc[dt] = __builtin_amdgcn_mfma_f32_16x16x32_bf16(vf1, pf1, oacc[dt], 0, 0, 0);
    }
    __builtin_amdgcn_s_setprio(0);
    __syncthreads();              // all waves done reading Kt/Vt
    if (mc0 + 64 < N_) {
      WRITEKV();                  // chunk mc0+64 (regs -> LDS; vmcnt auto)
      if (mc0 + 128 < N_) LOADKV(mc0 + 128);
      #pragma unroll
      for (int t = 0; t < 4; t++) bb[t] = bbn[t];
      __syncthreads();            // writes visible
    }
  }
  #undef LOADKV
  #undef WRITEKV
  l_run += __shfl_xor(l_run, 16, 64);
  l_run += __shfl_xor(l_run, 32, 64);
  float inv = 1.0f / l_run;
  const size_t row = (size_t)(b * N_ + qrow);
  #pragma unroll
  for (int dt = 0; dt < 8; dt++) {
    const int d0 = dt * 16 + ly * 4;
    us4 pk = { f2b(oacc[dt][0] * inv), f2b(oacc[dt][1] * inv),
               f2b(oacc[dt][2] * inv), f2b(oacc[dt][3] * inv) };
    if (d0 < 32) {
      *(us4*)&Hres[row * D_ + h * DH_ + d0] = pk;
    } else {
      const int c = (d0 - DH_) >> 5, dd = (d0 - DH_) & 31;
      *(us4*)&Vres[(row * 3 + c) * D_ + h * DH_ + dd] = pk;
    }
  }
}

// ---------------- fused ln2 + scaler (shuffle reduce) ------------------------
__global__ __launch_bounds__(256) void ln2scaler(const float* __restrict__ H,
    const float* __restrict__ g, const float* __restrict__ b,
    const float* __restrict__ Vp, us* __restrict__ scal) {
  __shared__ float p1[4], p2[4];
  size_t row = blockIdx.x;
  int j = threadIdx.x;
  float x = H[row * D_ + j];
  float a = x, c = x * x;
  #pragma unroll
  for (int o = 32; o > 0; o >>= 1) {
    a += __shfl_xor(a, o, 64);
    c += __shfl_xor(c, o, 64);
  }
  if ((j & 63) == 0) { p1[j >> 6] = a; p2[j >> 6] = c; }
  __syncthreads();
  float s1 = (p1[0] + p1[1]) + (p1[2] + p1[3]);
  float s2 = (p2[0] + p2[1]) + (p2[2] + p2[3]);
  float mean = s1 * (1.0f / D_);
  float var  = s2 * (1.0f / D_) - mean * mean;
  float inv  = rsqrtf(var + EPS_);
  scal[row * 512 + j] = f2b((x - mean) * inv * g[j] + b[j]);
  float va = Vp[(row * 3 + 0) * 512 + j];
  float c1 = Vp[(row * 3 + 1) * 512 + j];
  float c2 = Vp[(row * 3 + 2) * 512 + j];
  scal[row * 512 + D_ + j] = f2b(sqrtf(va * va + c1 * c1 + c2 * c2));
}

extern "C" void kernel_launch(void* const* d_in, const int* in_sizes, int n_in,
                              void* d_out, int out_size, void* d_ws, size_t ws_size,
                              hipStream_t stream) {
  const float* H_in = (const float*)d_in[0];
  const float* V_in = (const float*)d_in[1];
  const float* Db   = (const float*)d_in[2];
  const float* rbf  = (const float*)d_in[3];
  const float* ln1g = (const float*)d_in[5];
  const float* ln1b = (const float*)d_in[6];
  const float* ln2g = (const float*)d_in[7];
  const float* ln2b = (const float*)d_in[8];
  const float* Wq  = (const float*)d_in[9];
  const float* bq  = (const float*)d_in[10];
  const float* Wk  = (const float*)d_in[11];
  const float* bk  = (const float*)d_in[12];
  const float* Wv  = (const float*)d_in[13];
  const float* bv  = (const float*)d_in[14];
  const float* Wvv = (const float*)d_in[15];
  const float* Wo  = (const float*)d_in[16];
  const float* bo  = (const float*)d_in[17];
  const float* Wvo = (const float*)d_in[18];
  const float* Wlv = (const float*)d_in[19];
  const float* W1  = (const float*)d_in[20];
  const float* b1  = (const float*)d_in[21];
  const float* W2  = (const float*)d_in[22];
  const float* b2  = (const float*)d_in[23];

  const size_t HN = (size_t)B_ * N_ * D_;        // 1,048,576
  const size_t VN = HN * 3;
  float* Hs = (float*)d_out;
  float* Vs = (float*)d_out + HN;
  float* ws = (float*)d_ws;
  // ---- workspace (float offsets) ----
  us*    bias_b = (us*)ws;                          // [0, 4,194,304)
  us*    Vb     = (us*)(ws + 5177344);              // [5177344, 6750208) persistent
  us*    Hnb    = (us*)(ws + 6750208);              // [6750208, 7274496)
  us*    QKVb   = (us*)(ws + 7274496);              // [7274496, 11993088)
  us*    Vtb    = (us*)(ws + 11993088);             // [11993088, 14090240)
  us*    Vvb    = (us*)(ws + 14090240);             // [14090240, 14876672)
  us*    Hres_b = (us*)(ws + 6750208);              // reuse Hnb (post-attn)
  us*    Vres_b = (us*)(ws + 14090240);             // overlays Vvb (post-attn)
  float* Vp     = ws + 7274496;                     // [7274496, 13565952) post-attn
  us*    scal_b = (us*)(ws + 13565952);             // [13565952, 14614528) post-Wvo
  us*    midb   = (us*)(ws + 15014528);             // [15014528, 17111680)
  us*    Wb4    = (us*)(ws + 17111680);             // [17111680, 21043840) 4-layer weights

  // V state init (f32 copy + bf16 mirror) in one pass
  conv_copy<<<3072, 256, 0, stream>>>(V_in, Vs, Vb);

  const int ROWS  = B_ * N_;       // 4096
  static const int wKs[9] = {256,256,256,256,256,256,256,512,1024};
  static const int wNs[9] = {1024,1024,256,256,256,256,512,1024,512};
  static const unsigned wOff[9] = {0,262144,524288,589824,655360,720896,786432,917504,1441792};
  static const int wStart[10] = {0,64,128,144,160,176,192,224,352,480};
  static const int wLstr[9] = {262144,262144,65536,65536,65536,65536,131072,524288,524288};

  // all-layer weight conversion: one dispatch, 1920 blocks
  {
    WConvDesc dsc;
    const float* srcs[9] = {Wq, Wk, Wv, Wvv, Wo, Wvo, Wlv, W1, W2};
    for (int j = 0; j < 9; j++) {
      dsc.src[j] = srcs[j]; dsc.dst[j] = wOff[j];
      dsc.K[j] = wKs[j]; dsc.N[j] = wNs[j]; dsc.start[j] = wStart[j];
      dsc.lstride[j] = wLstr[j];
    }
    dsc.start[9] = wStart[9];
    wconv_kernel<<<480 * L_, 256, 0, stream>>>(dsc, Wb4);
  }
  // layer-0 ln1 reads H_in directly and materializes the H state copy
  ln_kernel<<<ROWS, 256, 0, stream>>>(H_in, ln1g, ln1b, Hnb, Hs);

  for (int l = 0; l < L_; ++l) {
    us* Wb = Wb4 + (size_t)l * 1966080u;

    // fused QKV GEMM + Vvv GEMM + bias precombine in one dispatch
    gemm_qkv<<<dim3(36, 66), 256, 0, stream>>>(
        Hnb, Wb + wOff[0], bq + l * 1024, bk + l * 1024, bv + l * 256,
        QKVb, rbf + (size_t)l * B_ * N_ * N_, Db, bias_b, FACTOR_ * LOG2E_,
        Vb, Wb + wOff[3], Vvb);
    pack_vattn_t<<<512, 256, 0, stream>>>(QKVb, Vvb, Vtb);
    attn_mfma<<<512, 256, 0, stream>>>(QKVb, Vtb, bias_b, Hres_b, Vres_b);
    gemm_wo<<<dim3(4, 256), 256, 0, stream>>>(
        Hres_b, Vres_b, Wb + wOff[4], Wb + wOff[5], bo + l * 256, Hs, Vs, Vb);
    gemm_v2<128,64,0,0,0,1,0,0,3><<<dim3(8, 96), 256, 0, stream>>>(
        Vb, Wb + wOff[6], nullptr, nullptr, nullptr, Vp, nullptr, 12288, 256, 512, 1.f);
    ln2scaler<<<ROWS, 256, 0, stream>>>(Hs, ln2g + l * D_, ln2b + l * D_, Vp, scal_b);
    gemm_v2<128,64,1,0,1,0,1,0,3><<<dim3(16, 32), 256, 0, stream>>>(
        scal_b, Wb + wOff[7], b1 + l * 1024, nullptr, nullptr, nullptr, midb, 4096, 512, 1024, 1.f);
    gemm_w2<<<dim3(8, 64), 256, 0, stream>>>(
        midb, Wb + wOff[8], b2 + l * 512, Vp, Hs, Vs, Vb);
    if (l < 3)
      ln_kernel<<<ROWS, 256, 0, stream>>>(Hs, ln1g + (l + 1) * D_,
                                          ln1b + (l + 1) * D_, Hnb, nullptr);
  }
}